// Round 2
// baseline (5846.857 us; speedup 1.0000x reference)
//
#include <hip/hip_runtime.h>

#define V 100000
#define NNZ 1600000

typedef unsigned short ushort_t;
typedef unsigned int uint_t;

__device__ __forceinline__ float bf2f(ushort_t u) {
    union { uint_t i; float f; } x; x.i = ((uint_t)u) << 16; return x.f;
}
__device__ __forceinline__ ushort_t f2bf(float f) {
    union { float f; uint_t i; } x; x.f = f;
    uint_t u = x.i;
    return (ushort_t)((u + 0x7fffu + ((u >> 16) & 1u)) >> 16);
}

// ---------------------------------------------------------------------------
// diagnostic: encode ws_size (MB) into out[0] when workspace is insufficient
// ---------------------------------------------------------------------------
__global__ void diag_k(float* __restrict__ out, float code) {
    if (threadIdx.x == 0 && blockIdx.x == 0) out[0] = code;
}

// ---------------------------------------------------------------------------
// x (B,64,V) f32  ->  x0 (V, 256) bf16, x0[v][b*64+c] = x[b][c][v]
// ---------------------------------------------------------------------------
__global__ __launch_bounds__(256) void pack_x0_k(const float* __restrict__ x,
                                                 ushort_t* __restrict__ x0) {
    __shared__ float tile[32][33];
    int v0 = blockIdx.x * 32, j0 = blockIdx.y * 32;
    int tx = threadIdx.x & 31, ty = threadIdx.x >> 5;
    for (int jj = ty; jj < 32; jj += 8)
        tile[jj][tx] = x[(size_t)(j0 + jj) * V + v0 + tx];
    __syncthreads();
    for (int vv = ty; vv < 32; vv += 8)
        x0[(size_t)(v0 + vv) * 256 + j0 + tx] = f2bf(tile[tx][vv]);
}

// ---------------------------------------------------------------------------
// CSR build: histogram -> 3-phase exclusive scan -> scatter
// ---------------------------------------------------------------------------
__global__ __launch_bounds__(256) void hist_k(const int* __restrict__ rows,
                                              int* __restrict__ counts) {
    int e = blockIdx.x * 256 + threadIdx.x;
    atomicAdd(&counts[rows[e]], 1);
}

__global__ __launch_bounds__(256) void scan1_k(const int* __restrict__ counts,
                                               int* __restrict__ bsums) {
    __shared__ int sd[256];
    int t = threadIdx.x;
    int v = blockIdx.x * 256 + t;
    sd[t] = (v < V) ? counts[v] : 0;
    __syncthreads();
    for (int s = 128; s > 0; s >>= 1) {
        if (t < s) sd[t] += sd[t + s];
        __syncthreads();
    }
    if (t == 0) bsums[blockIdx.x] = sd[0];
}

__global__ __launch_bounds__(512) void scan2_k(int* __restrict__ bsums, int nb) {
    __shared__ int sd[512];
    int t = threadIdx.x;
    int v = (t < nb) ? bsums[t] : 0;
    sd[t] = v;
    __syncthreads();
    for (int off = 1; off < 512; off <<= 1) {
        int a = (t >= off) ? sd[t - off] : 0;
        __syncthreads();
        sd[t] += a;
        __syncthreads();
    }
    if (t < nb) bsums[t] = sd[t] - v;  // exclusive
}

// writes rowptr AND cursor (avoids a d2d copy)
__global__ __launch_bounds__(256) void scan3_k(const int* __restrict__ counts,
                                               const int* __restrict__ bsums,
                                               int* __restrict__ rowptr,
                                               int* __restrict__ cursor) {
    __shared__ int sd[256];
    int t = threadIdx.x;
    int v = blockIdx.x * 256 + t;
    int c = (v < V) ? counts[v] : 0;
    sd[t] = c;
    __syncthreads();
    for (int off = 1; off < 256; off <<= 1) {
        int a = (t >= off) ? sd[t - off] : 0;
        __syncthreads();
        sd[t] += a;
        __syncthreads();
    }
    if (v < V) {
        int start = bsums[blockIdx.x] + sd[t] - c;
        rowptr[v] = start;
        cursor[v] = start;
    }
    if (v == 0) rowptr[V] = NNZ;
}

__global__ __launch_bounds__(256) void scatter_k(const int* __restrict__ rows,
                                                 const int* __restrict__ cols,
                                                 const float* __restrict__ vals,
                                                 int* __restrict__ cursor,
                                                 int* __restrict__ scol,
                                                 float* __restrict__ sval) {
    int e = blockIdx.x * 256 + threadIdx.x;
    int r = rows[e];
    int pos = atomicAdd(&cursor[r], 1);
    scol[pos] = cols[e];
    sval[pos] = vals[e];
}

// ---------------------------------------------------------------------------
// SpMM: out[v][f] = alpha * sum_e val_e * nY(y[col_e][f]) + beta * nZ(z[v][f])
// out may alias z (each (v,f) is read then written by exactly one thread;
// gathers only touch y). Tables bf16; fp32 accumulate; optional BN affine.
// ---------------------------------------------------------------------------
template <int F>
__global__ __launch_bounds__(256) void spmm_k(const int* __restrict__ rowptr,
                                              const int* __restrict__ scol,
                                              const float* __restrict__ sval,
                                              const ushort_t* __restrict__ y,
                                              const ushort_t* __restrict__ z,
                                              const float* __restrict__ ss,
                                              int normY, int normZ,
                                              float alpha, float beta,
                                              ushort_t* __restrict__ out) {
    constexpr int LPR = F / 2;           // lanes per row
    constexpr int RPB = 256 / LPR;       // rows per block
    int tid = threadIdx.x;
    int fi = tid % LPR;
    int v = blockIdx.x * RPB + tid / LPR;
    int f0 = fi * 2;
    float sc0 = 1.f, sh0 = 0.f, sc1 = 1.f, sh1 = 0.f;
    if (normY) {
        int c0 = f0 & 127;
        sc0 = ss[c0];      sh0 = ss[128 + c0];
        sc1 = ss[c0 + 1];  sh1 = ss[128 + c0 + 1];
    }
    int e0 = rowptr[v], e1 = rowptr[v + 1];
    float a0 = 0.f, a1 = 0.f;
    for (int e = e0; e < e1; ++e) {
        int col = scol[e];
        float val = sval[e];
        uint_t p = *(const uint_t*)(y + (size_t)col * F + f0);
        float y0v = bf2f((ushort_t)(p & 0xffffu));
        float y1v = bf2f((ushort_t)(p >> 16));
        a0 += val * (y0v * sc0 + sh0);
        a1 += val * (y1v * sc1 + sh1);
    }
    float r0 = alpha * a0, r1 = alpha * a1;
    if (z) {
        float zc0 = 1.f, zh0 = 0.f, zc1 = 1.f, zh1 = 0.f;
        if (normZ) {
            int c0 = f0 & 127;
            zc0 = ss[c0];      zh0 = ss[128 + c0];
            zc1 = ss[c0 + 1];  zh1 = ss[128 + c0 + 1];
        }
        uint_t p = *(const uint_t*)(z + (size_t)v * F + f0);
        float z0 = bf2f((ushort_t)(p & 0xffffu)) * zc0 + zh0;
        float z1 = bf2f((ushort_t)(p >> 16)) * zc1 + zh1;
        r0 += beta * z0;
        r1 += beta * z1;
    }
    uint_t packed = (uint_t)f2bf(r0) | ((uint_t)f2bf(r1) << 16);
    *(uint_t*)(out + (size_t)v * F + f0) = packed;
}

// ---------------------------------------------------------------------------
// GEMM1 (per-k accumulate): rb[v][b*128+ch] (+)= xk[v][b*64+i] * w1k[i][ch]
// first: overwrite rb (ws is poisoned). last: + bias, ReLU, BN stats.
// Tile 64v x 128ch per (v-tile, b); 256 thr; micro 8r x 4c.
// ---------------------------------------------------------------------------
__global__ __launch_bounds__(256) void gemm1_k(const ushort_t* __restrict__ xk,
                                               const float* __restrict__ w1k,
                                               const float* __restrict__ b1,
                                               ushort_t* __restrict__ rb,
                                               float* __restrict__ stats,
                                               int first, int last) {
    __shared__ float Asub[64 * 68];
    __shared__ float Wsub[64 * 128];
    __shared__ float s_sum[128];
    __shared__ float s_sq[128];
    int tid = threadIdx.x;
    int tc = tid & 31, tr = tid >> 5;
    int b = blockIdx.y;
    int v0 = blockIdx.x * 64;
    if (tid < 128) { s_sum[tid] = 0.f; s_sq[tid] = 0.f; }
    float acc[8][4];
#pragma unroll
    for (int j = 0; j < 8; ++j)
#pragma unroll
        for (int c = 0; c < 4; ++c) acc[j][c] = 0.f;

#pragma unroll
    for (int it = 0; it < 16; ++it) {
        int idx = it * 256 + tid;
        int r = idx >> 6, i = idx & 63;
        int v = v0 + r;
        Asub[r * 68 + i] = (v < V) ? bf2f(xk[(size_t)v * 256 + b * 64 + i]) : 0.f;
    }
#pragma unroll
    for (int it = 0; it < 32; ++it) {
        int idx = it * 256 + tid;
        Wsub[idx] = w1k[idx];
    }
    __syncthreads();
    for (int i = 0; i < 64; i += 4) {
        float4 wv0 = *(const float4*)&Wsub[(i + 0) * 128 + 4 * tc];
        float4 wv1 = *(const float4*)&Wsub[(i + 1) * 128 + 4 * tc];
        float4 wv2 = *(const float4*)&Wsub[(i + 2) * 128 + 4 * tc];
        float4 wv3 = *(const float4*)&Wsub[(i + 3) * 128 + 4 * tc];
#pragma unroll
        for (int j = 0; j < 8; ++j) {
            float4 av = *(const float4*)&Asub[(tr + 8 * j) * 68 + i];
            acc[j][0] += av.x * wv0.x + av.y * wv1.x + av.z * wv2.x + av.w * wv3.x;
            acc[j][1] += av.x * wv0.y + av.y * wv1.y + av.z * wv2.y + av.w * wv3.y;
            acc[j][2] += av.x * wv0.z + av.y * wv1.z + av.z * wv2.z + av.w * wv3.z;
            acc[j][3] += av.x * wv0.w + av.y * wv1.w + av.z * wv2.w + av.w * wv3.w;
        }
    }

    float bias[4] = {0.f, 0.f, 0.f, 0.f};
    if (last) {
#pragma unroll
        for (int c = 0; c < 4; ++c) bias[c] = b1[4 * tc + c];
    }
    float lsum[4] = {0.f, 0.f, 0.f, 0.f}, lsq[4] = {0.f, 0.f, 0.f, 0.f};
#pragma unroll
    for (int j = 0; j < 8; ++j) {
        int v = v0 + tr + 8 * j;
        if (v < V) {
            ushort_t* p = rb + (size_t)v * 512 + b * 128 + 4 * tc;
            float prev[4] = {0.f, 0.f, 0.f, 0.f};
            if (!first) {
                uint2 pv = *(const uint2*)p;
                prev[0] = bf2f((ushort_t)(pv.x & 0xffffu));
                prev[1] = bf2f((ushort_t)(pv.x >> 16));
                prev[2] = bf2f((ushort_t)(pv.y & 0xffffu));
                prev[3] = bf2f((ushort_t)(pv.y >> 16));
            }
            ushort_t pk[4];
#pragma unroll
            for (int c = 0; c < 4; ++c) {
                float val = acc[j][c] + prev[c];
                if (last) {
                    val = fmaxf(val + bias[c], 0.f);
                    lsum[c] += val;
                    lsq[c] += val * val;
                }
                pk[c] = f2bf(val);
            }
            uint2 st;
            st.x = (uint_t)pk[0] | ((uint_t)pk[1] << 16);
            st.y = (uint_t)pk[2] | ((uint_t)pk[3] << 16);
            *(uint2*)p = st;
        }
    }
    if (last) {
#pragma unroll
        for (int c = 0; c < 4; ++c) {
            atomicAdd(&s_sum[4 * tc + c], lsum[c]);
            atomicAdd(&s_sq[4 * tc + c], lsq[c]);
        }
        __syncthreads();
        if (tid < 128) {
            atomicAdd(&stats[tid], s_sum[tid]);
            atomicAdd(&stats[128 + tid], s_sq[tid]);
        }
    }
}

// ---------------------------------------------------------------------------
// BN finalize: per-channel scale/shift from stats
// ---------------------------------------------------------------------------
__global__ void finalize_k(const float* __restrict__ stats,
                           const float* __restrict__ gamma,
                           const float* __restrict__ beta,
                           float* __restrict__ ss) {
    int c = threadIdx.x;  // 128 threads
    float n = (float)(4 * V);
    float mean = stats[c] / n;
    float var = stats[128 + c] / n - mean * mean;
    float inv = rsqrtf(var + 1e-5f);
    float sc = gamma[c] * inv;
    ss[c] = sc;
    ss[128 + c] = beta[c] - mean * sc;
}

// ---------------------------------------------------------------------------
// GEMM2 (per-k accumulate into d_out (B,64,V) f32):
//   out[b][o][v] (+)= nA(ya[v][b*128+ch]) * w2k[ch][o]
// first: overwrite. last: + b2 + residual + ReLU.
// Tile 64v x 64o per (v-tile, b); 256 thr; micro 4r x 4c; K=128 in 2 halves.
// ---------------------------------------------------------------------------
__global__ __launch_bounds__(256) void gemm2_k(const ushort_t* __restrict__ ya,
                                               const float* __restrict__ w2k,
                                               const float* __restrict__ b2,
                                               const float* __restrict__ xres,
                                               const float* __restrict__ ss,
                                               float* __restrict__ out,
                                               int normA, int first, int last) {
    __shared__ float Asub[64 * 68];
    __shared__ float Wsub[64 * 64];
    int tid = threadIdx.x;
    int tr = tid & 15, tc = tid >> 4;
    int b = blockIdx.y;
    int v0 = blockIdx.x * 64;
    float acc[4][4];
#pragma unroll
    for (int j = 0; j < 4; ++j)
#pragma unroll
        for (int c = 0; c < 4; ++c) acc[j][c] = 0.f;

    for (int half = 0; half < 2; ++half) {
        int c0 = half * 64;
#pragma unroll
        for (int it = 0; it < 16; ++it) {
            int idx = it * 256 + tid;
            int r = idx >> 6, i = idx & 63;
            int v = v0 + r;
            float val = 0.f;
            if (v < V) {
                val = bf2f(ya[(size_t)v * 512 + b * 128 + c0 + i]);
                if (normA) val = val * ss[c0 + i] + ss[128 + c0 + i];
            }
            Asub[r * 68 + i] = val;
        }
#pragma unroll
        for (int it = 0; it < 16; ++it) {
            int idx = it * 256 + tid;
            Wsub[idx] = w2k[(size_t)c0 * 64 + idx];
        }
        __syncthreads();
        for (int i = 0; i < 64; i += 4) {
            float4 wv0 = *(const float4*)&Wsub[(i + 0) * 64 + 4 * tc];
            float4 wv1 = *(const float4*)&Wsub[(i + 1) * 64 + 4 * tc];
            float4 wv2 = *(const float4*)&Wsub[(i + 2) * 64 + 4 * tc];
            float4 wv3 = *(const float4*)&Wsub[(i + 3) * 64 + 4 * tc];
#pragma unroll
            for (int j = 0; j < 4; ++j) {
                float4 av = *(const float4*)&Asub[(tr + 16 * j) * 68 + i];
                acc[j][0] += av.x * wv0.x + av.y * wv1.x + av.z * wv2.x + av.w * wv3.x;
                acc[j][1] += av.x * wv0.y + av.y * wv1.y + av.z * wv2.y + av.w * wv3.y;
                acc[j][2] += av.x * wv0.z + av.y * wv1.z + av.z * wv2.z + av.w * wv3.z;
                acc[j][3] += av.x * wv0.w + av.y * wv1.w + av.z * wv2.w + av.w * wv3.w;
            }
        }
        __syncthreads();
    }

#pragma unroll
    for (int j = 0; j < 4; ++j) {
        int v = v0 + tr + 16 * j;
        if (v < V) {
#pragma unroll
            for (int c = 0; c < 4; ++c) {
                int o = 4 * tc + c;
                size_t idx = (size_t)(b * 64 + o) * V + v;
                float val = acc[j][c];
                if (!first) val += out[idx];
                if (last) val = fmaxf(val + b2[o] + xres[idx], 0.f);
                out[idx] = val;
            }
        }
    }
}

// ---------------------------------------------------------------------------
extern "C" void kernel_launch(void* const* d_in, const int* in_sizes, int n_in,
                              void* d_out, int out_size, void* d_ws, size_t ws_size,
                              hipStream_t stream) {
    const float* x = (const float*)d_in[0];
    const int* lap_rows = (const int*)d_in[1];
    const int* lap_cols = (const int*)d_in[2];
    const float* lap_vals = (const float*)d_in[3];
    const float* w1 = (const float*)d_in[4];
    const float* b1 = (const float*)d_in[5];
    const float* bn_gamma = (const float*)d_in[6];
    const float* bn_beta = (const float*)d_in[7];
    const float* w2 = (const float*)d_in[8];
    const float* b2 = (const float*)d_in[9];
    float* out = (float*)d_out;

    char* ws = (char*)d_ws;
    size_t off = 0;
    auto alloc = [&](size_t bytes) {
        size_t r = off;
        off = (off + bytes + 255) & ~(size_t)255;
        return r;
    };
    size_t reg1_off = alloc((size_t)V * 512 * 2);  // chain1 A+B / chain2 C (102.4 MB)
    size_t rb_off   = alloc((size_t)V * 512 * 2);  // h / chain2 ping-pong (102.4 MB)
    size_t rp_off   = alloc((size_t)(V + 1) * 4);
    size_t cur_off  = alloc((size_t)V * 4);
    size_t scol_off = alloc((size_t)NNZ * 4);
    size_t sval_off = alloc((size_t)NNZ * 4);
    size_t st_off   = alloc(256 * 4);
    size_t ss_off   = alloc(256 * 4);
    size_t bs_off   = alloc(512 * 4);

    if (ws_size < off) {
        // workspace too small: encode its size (MB) into out[0] for diagnosis
        diag_k<<<1, 64, 0, stream>>>(out, 1000.f + (float)(ws_size >> 20));
        return;
    }

    ushort_t* A = (ushort_t*)(ws + reg1_off);       // chain1 x_prev (V x 256)
    ushort_t* Bb = A + (size_t)V * 256;             // chain1 x_cur  (V x 256)
    ushort_t* C = (ushort_t*)(ws + reg1_off);       // chain2 buffer (V x 512)
    ushort_t* rb = (ushort_t*)(ws + rb_off);        // h / chain2    (V x 512)
    int* rowptr = (int*)(ws + rp_off);
    int* cursor = (int*)(ws + cur_off);             // doubles as counts
    int* scol = (int*)(ws + scol_off);
    float* sval = (float*)(ws + sval_off);
    float* stats = (float*)(ws + st_off);
    float* ss = (float*)(ws + ss_off);
    int* bsums = (int*)(ws + bs_off);

    const int NB = (V + 255) / 256;  // 391
    const ushort_t* nullu = (const ushort_t*)nullptr;

    hipMemsetAsync(cursor, 0, (size_t)V * 4, stream);
    hipMemsetAsync(stats, 0, 256 * 4, stream);

    pack_x0_k<<<dim3(V / 32, 8), 256, 0, stream>>>(x, A);
    hist_k<<<NNZ / 256, 256, 0, stream>>>(lap_rows, cursor);
    scan1_k<<<NB, 256, 0, stream>>>(cursor, bsums);
    scan2_k<<<1, 512, 0, stream>>>(bsums, NB);
    scan3_k<<<NB, 256, 0, stream>>>(cursor, bsums, rowptr, cursor);
    scatter_k<<<NNZ / 256, 256, 0, stream>>>(lap_rows, lap_cols, lap_vals, cursor, scol, sval);

    dim3 gg((V + 63) / 64, 4);

    // ---- Chain 1 (F=256), h accumulated per-k into rb ----
    gemm1_k<<<gg, 256, 0, stream>>>(A, w1 + 0 * 8192, b1, rb, stats, 1, 0);      // h = x0 W0
    spmm_k<256><<<V / 2, 256, 0, stream>>>(rowptr, scol, sval, A, nullu, ss, 0, 0, 1.f, 0.f, Bb);   // x1 = L x0
    gemm1_k<<<gg, 256, 0, stream>>>(Bb, w1 + 1 * 8192, b1, rb, stats, 0, 0);     // h += x1 W1
    spmm_k<256><<<V / 2, 256, 0, stream>>>(rowptr, scol, sval, Bb, A, ss, 0, 0, 2.f, -1.f, A);      // x2 = 2Lx1 - x0
    gemm1_k<<<gg, 256, 0, stream>>>(A, w1 + 2 * 8192, b1, rb, stats, 0, 0);      // h += x2 W2
    spmm_k<256><<<V / 2, 256, 0, stream>>>(rowptr, scol, sval, A, Bb, ss, 0, 0, 2.f, -1.f, Bb);     // x3 = 2Lx2 - x1
    gemm1_k<<<gg, 256, 0, stream>>>(Bb, w1 + 3 * 8192, b1, rb, stats, 0, 1);     // h += x3 W3; relu+stats

    finalize_k<<<1, 128, 0, stream>>>(stats, bn_gamma, bn_beta, ss);

    // ---- Chain 2 (F=512), out accumulated per-k into d_out ----
    gemm2_k<<<gg, 256, 0, stream>>>(rb, w2 + 0 * 8192, b2, x, ss, out, 1, 1, 0); // out = y0^ W0
    spmm_k<512><<<V, 256, 0, stream>>>(rowptr, scol, sval, rb, nullu, ss, 1, 0, 1.f, 0.f, C);       // y1 = L y0^
    gemm2_k<<<gg, 256, 0, stream>>>(C, w2 + 1 * 8192, b2, x, ss, out, 0, 0, 0);  // out += y1 W1
    spmm_k<512><<<V, 256, 0, stream>>>(rowptr, scol, sval, C, rb, ss, 0, 1, 2.f, -1.f, rb);         // y2 = 2Ly1 - y0^
    gemm2_k<<<gg, 256, 0, stream>>>(rb, w2 + 2 * 8192, b2, x, ss, out, 0, 0, 0); // out += y2 W2
    spmm_k<512><<<V, 256, 0, stream>>>(rowptr, scol, sval, rb, C, ss, 0, 0, 2.f, -1.f, C);          // y3 = 2Ly2 - y1
    gemm2_k<<<gg, 256, 0, stream>>>(C, w2 + 3 * 8192, b2, x, ss, out, 0, 0, 1);  // out += y3 W3; +b2+res, relu
}

// Round 3
// 3462.916 us; speedup vs baseline: 1.6884x; 1.6884x over previous
//
#include <hip/hip_runtime.h>

#define V 100000
#define NNZ 1600000

typedef unsigned short ushort_t;
typedef unsigned int uint_t;
typedef __attribute__((ext_vector_type(4))) float f32x4;
typedef __attribute__((ext_vector_type(8))) short bf16x8;

__device__ __forceinline__ float bf2f(ushort_t u) {
    union { uint_t i; float f; } x; x.i = ((uint_t)u) << 16; return x.f;
}
__device__ __forceinline__ ushort_t f2bf(float f) {
    union { float f; uint_t i; } x; x.f = f;
    uint_t u = x.i;
    return (ushort_t)((u + 0x7fffu + ((u >> 16) & 1u)) >> 16);
}

__global__ void diag_k(float* __restrict__ out, float code) {
    if (threadIdx.x == 0 && blockIdx.x == 0) out[0] = code;
}

// ---------------------------------------------------------------------------
// x (B,64,V) f32  ->  x0 (V, 256) bf16, x0[v][b*64+c] = x[b][c][v]
// ---------------------------------------------------------------------------
__global__ __launch_bounds__(256) void pack_x0_k(const float* __restrict__ x,
                                                 ushort_t* __restrict__ x0) {
    __shared__ float tile[32][33];
    int v0 = blockIdx.x * 32, j0 = blockIdx.y * 32;
    int tx = threadIdx.x & 31, ty = threadIdx.x >> 5;
    for (int jj = ty; jj < 32; jj += 8)
        tile[jj][tx] = x[(size_t)(j0 + jj) * V + v0 + tx];
    __syncthreads();
    for (int vv = ty; vv < 32; vv += 8)
        x0[(size_t)(v0 + vv) * 256 + j0 + tx] = f2bf(tile[tx][vv]);
}

// ---------------------------------------------------------------------------
// weights -> bf16, MFMA-B/A-fragment-swizzled
// wp1[L][kb(4)][q(4)][ch(128)][j(8)]  = w1[L*2+(k>>6)][k&63][ch], k=kb*32+q*8+j
// wp2[L][kb(8)][q(4)][o(64)][j(8)]    = w2[L*2+(k>>7)][k&127][o], k=kb*32+q*8+j
// ---------------------------------------------------------------------------
__global__ __launch_bounds__(256) void prep_w_k(const float* __restrict__ w1,
                                                const float* __restrict__ w2,
                                                ushort_t* __restrict__ wp1,
                                                ushort_t* __restrict__ wp2) {
    int idx = blockIdx.x * 256 + threadIdx.x;
    if (idx < 32768) {
        int f = idx;
        int j = f & 7, ch = (f >> 3) & 127, q = (f >> 10) & 3, kb = (f >> 12) & 3, L = (f >> 14) & 1;
        int k = kb * 32 + q * 8 + j;
        int t = L * 2 + (k >> 6), i = k & 63;
        wp1[idx] = f2bf(w1[((size_t)t * 64 + i) * 128 + ch]);
    } else {
        int f = idx - 32768;
        int j = f & 7, o = (f >> 3) & 63, q = (f >> 9) & 3, kb = (f >> 11) & 7, L = (f >> 14) & 1;
        int k = kb * 32 + q * 8 + j;
        int t = L * 2 + (k >> 7), ch = k & 127;
        wp2[f] = f2bf(w2[((size_t)t * 128 + ch) * 64 + o]);
    }
}

// ---------------------------------------------------------------------------
// CSR build: histogram -> 3-phase exclusive scan -> scatter (edges as int2)
// ---------------------------------------------------------------------------
__global__ __launch_bounds__(256) void hist_k(const int* __restrict__ rows,
                                              int* __restrict__ counts) {
    int e = blockIdx.x * 256 + threadIdx.x;
    atomicAdd(&counts[rows[e]], 1);
}

__global__ __launch_bounds__(256) void scan1_k(const int* __restrict__ counts,
                                               int* __restrict__ bsums) {
    __shared__ int sd[256];
    int t = threadIdx.x;
    int v = blockIdx.x * 256 + t;
    sd[t] = (v < V) ? counts[v] : 0;
    __syncthreads();
    for (int s = 128; s > 0; s >>= 1) {
        if (t < s) sd[t] += sd[t + s];
        __syncthreads();
    }
    if (t == 0) bsums[blockIdx.x] = sd[0];
}

__global__ __launch_bounds__(512) void scan2_k(int* __restrict__ bsums, int nb) {
    __shared__ int sd[512];
    int t = threadIdx.x;
    int v = (t < nb) ? bsums[t] : 0;
    sd[t] = v;
    __syncthreads();
    for (int off = 1; off < 512; off <<= 1) {
        int a = (t >= off) ? sd[t - off] : 0;
        __syncthreads();
        sd[t] += a;
        __syncthreads();
    }
    if (t < nb) bsums[t] = sd[t] - v;  // exclusive
}

__global__ __launch_bounds__(256) void scan3_k(const int* __restrict__ counts,
                                               const int* __restrict__ bsums,
                                               int* __restrict__ rowptr,
                                               int* __restrict__ cursor) {
    __shared__ int sd[256];
    int t = threadIdx.x;
    int v = blockIdx.x * 256 + t;
    int c = (v < V) ? counts[v] : 0;
    sd[t] = c;
    __syncthreads();
    for (int off = 1; off < 256; off <<= 1) {
        int a = (t >= off) ? sd[t - off] : 0;
        __syncthreads();
        sd[t] += a;
        __syncthreads();
    }
    if (v < V) {
        int start = bsums[blockIdx.x] + sd[t] - c;
        rowptr[v] = start;
        cursor[v] = start;
    }
    if (v == 0) rowptr[V] = NNZ;
}

__global__ __launch_bounds__(256) void scatter_k(const int* __restrict__ rows,
                                                 const int* __restrict__ cols,
                                                 const float* __restrict__ vals,
                                                 int* __restrict__ cursor,
                                                 int2* __restrict__ edges) {
    int e = blockIdx.x * 256 + threadIdx.x;
    int r = rows[e];
    int pos = atomicAdd(&cursor[r], 1);
    edges[pos] = make_int2(cols[e], __float_as_int(vals[e]));
}

// ---------------------------------------------------------------------------
// SpMM: out[v][f] = alpha * sum_e val_e * nY(y[col_e][f]) + beta * nZ(z[v][f])
// out may alias z. Tables bf16; fp32 accumulate; optional BN affine.
// ---------------------------------------------------------------------------
template <int F>
__global__ __launch_bounds__(256) void spmm_k(const int* __restrict__ rowptr,
                                              const int2* __restrict__ edges,
                                              const ushort_t* __restrict__ y,
                                              const ushort_t* __restrict__ z,
                                              const float* __restrict__ ss,
                                              int normY, int normZ,
                                              float alpha, float beta,
                                              ushort_t* __restrict__ out) {
    constexpr int LPR = F / 2;
    constexpr int RPB = 256 / LPR;
    int tid = threadIdx.x;
    int fi = tid % LPR;
    int v = blockIdx.x * RPB + tid / LPR;
    int f0 = fi * 2;
    float sc0 = 1.f, sh0 = 0.f, sc1 = 1.f, sh1 = 0.f;
    if (normY) {
        int c0 = f0 & 127;
        sc0 = ss[c0];      sh0 = ss[128 + c0];
        sc1 = ss[c0 + 1];  sh1 = ss[128 + c0 + 1];
    }
    int e0 = rowptr[v], e1 = rowptr[v + 1];
    float a0 = 0.f, a1 = 0.f;
    for (int e = e0; e < e1; ++e) {
        int2 ed = edges[e];
        int col = ed.x;
        float val = __int_as_float(ed.y);
        uint_t p = *(const uint_t*)(y + (size_t)col * F + f0);
        float y0v = bf2f((ushort_t)(p & 0xffffu));
        float y1v = bf2f((ushort_t)(p >> 16));
        a0 += val * (y0v * sc0 + sh0);
        a1 += val * (y1v * sc1 + sh1);
    }
    float r0 = alpha * a0, r1 = alpha * a1;
    if (z) {
        float zc0 = 1.f, zh0 = 0.f, zc1 = 1.f, zh1 = 0.f;
        if (normZ) {
            int c0 = f0 & 127;
            zc0 = ss[c0];      zh0 = ss[128 + c0];
            zc1 = ss[c0 + 1];  zh1 = ss[128 + c0 + 1];
        }
        uint_t p = *(const uint_t*)(z + (size_t)v * F + f0);
        float z0 = bf2f((ushort_t)(p & 0xffffu)) * zc0 + zh0;
        float z1 = bf2f((ushort_t)(p >> 16)) * zc1 + zh1;
        r0 += beta * z0;
        r1 += beta * z1;
    }
    uint_t packed = (uint_t)f2bf(r0) | ((uint_t)f2bf(r1) << 16);
    *(uint_t*)(out + (size_t)v * F + f0) = packed;
}

// ---------------------------------------------------------------------------
// GEMM1 (MFMA): rb[v][b*128+ch] (+)= t0[v][b*64+i]*W(k0) + t1[v][b*64+i]*W(k0+1)
// K=128 (two 64-blocks). Block: 64v x 128ch, 4 waves (16v each).
// wp pre-swizzled: offset ((kb*4+q)*128 + ch)*8 + j.
// last: +bias, ReLU, BN-stats.
// ---------------------------------------------------------------------------
__global__ __launch_bounds__(256) void gemm1_mfma(const ushort_t* __restrict__ t0,
                                                  const ushort_t* __restrict__ t1,
                                                  const ushort_t* __restrict__ wp,
                                                  const float* __restrict__ b1,
                                                  ushort_t* __restrict__ rb,
                                                  float* __restrict__ stats,
                                                  int first, int last) {
    __shared__ float s_sum[128];
    __shared__ float s_sq[128];
    int tid = threadIdx.x;
    int l = tid & 63, w = tid >> 6;
    int q = l >> 4, n16 = l & 15;
    int b = blockIdx.y;
    int v0 = blockIdx.x * 64;
    if (last && tid < 128) { s_sum[tid] = 0.f; s_sq[tid] = 0.f; }
    int vrow = v0 + w * 16 + n16;
    int vc = vrow < V ? vrow : V - 1;

    f32x4 acc[8];
#pragma unroll
    for (int ct = 0; ct < 8; ++ct) acc[ct] = (f32x4){0.f, 0.f, 0.f, 0.f};

#pragma unroll
    for (int kb = 0; kb < 4; ++kb) {
        const ushort_t* tab = (kb < 2) ? t0 : t1;
        bf16x8 a = *(const bf16x8*)(tab + (size_t)vc * 256 + b * 64 + (kb & 1) * 32 + q * 8);
#pragma unroll
        for (int ct = 0; ct < 8; ++ct) {
            bf16x8 bf = *(const bf16x8*)(wp + (size_t)(((kb * 4 + q) * 128) + ct * 16 + n16) * 8);
            acc[ct] = __builtin_amdgcn_mfma_f32_16x16x32_bf16(a, bf, acc[ct], 0, 0, 0);
        }
    }

    float ls[8], lq[8];
#pragma unroll
    for (int ct = 0; ct < 8; ++ct) {
        ls[ct] = 0.f; lq[ct] = 0.f;
        float bc = last ? b1[ct * 16 + n16] : 0.f;
#pragma unroll
        for (int r = 0; r < 4; ++r) {
            int v = v0 + w * 16 + q * 4 + r;
            bool valid = v < V;
            float val = acc[ct][r];
            ushort_t* p = rb + (size_t)(valid ? v : 0) * 512 + b * 128 + ct * 16 + n16;
            if (!first && valid) val += bf2f(*p);
            if (last) {
                val = fmaxf(val + bc, 0.f);
                if (valid) { ls[ct] += val; lq[ct] += val * val; }
            }
            if (valid) *p = f2bf(val);
        }
    }
    if (last) {
        __syncthreads();
#pragma unroll
        for (int ct = 0; ct < 8; ++ct) {
            atomicAdd(&s_sum[ct * 16 + n16], ls[ct]);
            atomicAdd(&s_sq[ct * 16 + n16], lq[ct]);
        }
        __syncthreads();
        if (tid < 128) {
            atomicAdd(&stats[tid], s_sum[tid]);
            atomicAdd(&stats[128 + tid], s_sq[tid]);
        }
    }
}

__global__ void finalize_k(const float* __restrict__ stats,
                           const float* __restrict__ gamma,
                           const float* __restrict__ beta,
                           float* __restrict__ ss) {
    int c = threadIdx.x;  // 128 threads
    float n = (float)(4 * V);
    float mean = stats[c] / n;
    float var = stats[128 + c] / n - mean * mean;
    float inv = rsqrtf(var + 1e-5f);
    float sc = gamma[c] * inv;
    ss[c] = sc;
    ss[128 + c] = beta[c] - mean * sc;
}

// ---------------------------------------------------------------------------
// GEMM2 (MFMA): out[b][o][v] (+)= sum_ch W2(k)[ch][o]*Y(k)[v][b*128+ch], 2 terms
// D[o][v]: A=weights (m=o), B=Y (n=v). K=256. Block: 64o x 128v, 4 waves.
// wp pre-swizzled: offset ((kb*4+q)*64 + o)*8 + j. norm0: BN affine on t0.
// last: +b2 +residual, ReLU.
// ---------------------------------------------------------------------------
__global__ __launch_bounds__(256) void gemm2_mfma(const ushort_t* __restrict__ t0,
                                                  const ushort_t* __restrict__ t1,
                                                  const ushort_t* __restrict__ wp,
                                                  const float* __restrict__ b2,
                                                  const float* __restrict__ xres,
                                                  const float* __restrict__ ss,
                                                  float* __restrict__ out,
                                                  int norm0, int first, int last) {
    __shared__ float s_ss[256];
    int tid = threadIdx.x;
    s_ss[tid] = ss[tid];
    __syncthreads();
    int l = tid & 63, w = tid >> 6;
    int q = l >> 4, n16 = l & 15;
    int b = blockIdx.y;
    int v0 = blockIdx.x * 128;

    f32x4 acc[4][2];
#pragma unroll
    for (int rt = 0; rt < 4; ++rt)
#pragma unroll
        for (int c = 0; c < 2; ++c) acc[rt][c] = (f32x4){0.f, 0.f, 0.f, 0.f};

    int vcol[2];
#pragma unroll
    for (int c = 0; c < 2; ++c) {
        int v = v0 + (w * 2 + c) * 16 + n16;
        vcol[c] = v < V ? v : V - 1;
    }

#pragma unroll
    for (int kb = 0; kb < 8; ++kb) {
        const ushort_t* tab = (kb < 4) ? t0 : t1;
        int nrm = (kb < 4) ? norm0 : 0;
        int chl = (kb & 3) * 32 + q * 8;
        bf16x8 bfr[2];
#pragma unroll
        for (int c = 0; c < 2; ++c) {
            bf16x8 t = *(const bf16x8*)(tab + (size_t)vcol[c] * 512 + b * 128 + chl);
            if (nrm) {
#pragma unroll
                for (int j = 0; j < 8; ++j) {
                    float f = bf2f((ushort_t)t[j]);
                    f = f * s_ss[chl + j] + s_ss[128 + chl + j];
                    t[j] = (short)f2bf(f);
                }
            }
            bfr[c] = t;
        }
#pragma unroll
        for (int rt = 0; rt < 4; ++rt) {
            bf16x8 af = *(const bf16x8*)(wp + (size_t)(((kb * 4 + q) * 64) + rt * 16 + n16) * 8);
#pragma unroll
            for (int c = 0; c < 2; ++c)
                acc[rt][c] = __builtin_amdgcn_mfma_f32_16x16x32_bf16(af, bfr[c], acc[rt][c], 0, 0, 0);
        }
    }

#pragma unroll
    for (int rt = 0; rt < 4; ++rt)
#pragma unroll
        for (int c = 0; c < 2; ++c) {
            int v = v0 + (w * 2 + c) * 16 + n16;
            bool valid = v < V;
#pragma unroll
            for (int r = 0; r < 4; ++r) {
                int o = rt * 16 + q * 4 + r;
                size_t idx = (size_t)(b * 64 + o) * V + v;
                float val = acc[rt][c][r];
                if (valid) {
                    if (!first) val += out[idx];
                    if (last) val = fmaxf(val + b2[o] + xres[idx], 0.f);
                    out[idx] = val;
                }
            }
        }
}

// ---------------------------------------------------------------------------
extern "C" void kernel_launch(void* const* d_in, const int* in_sizes, int n_in,
                              void* d_out, int out_size, void* d_ws, size_t ws_size,
                              hipStream_t stream) {
    const float* x = (const float*)d_in[0];
    const int* lap_rows = (const int*)d_in[1];
    const int* lap_cols = (const int*)d_in[2];
    const float* lap_vals = (const float*)d_in[3];
    const float* w1 = (const float*)d_in[4];
    const float* b1 = (const float*)d_in[5];
    const float* bn_gamma = (const float*)d_in[6];
    const float* bn_beta = (const float*)d_in[7];
    const float* w2 = (const float*)d_in[8];
    const float* b2 = (const float*)d_in[9];
    float* out = (float*)d_out;

    char* ws = (char*)d_ws;
    size_t off = 0;
    auto alloc = [&](size_t bytes) {
        size_t r = off;
        off = (off + bytes + 255) & ~(size_t)255;
        return r;
    };
    size_t reg1_off = alloc((size_t)V * 512 * 2);  // chain1 A+B / chain2 C (102.4 MB)
    size_t rb_off   = alloc((size_t)V * 512 * 2);  // h / chain2 ping-pong (102.4 MB)
    size_t rp_off   = alloc((size_t)(V + 1) * 4);
    size_t cur_off  = alloc((size_t)V * 4);
    size_t ed_off   = alloc((size_t)NNZ * 8);
    size_t st_off   = alloc(256 * 4);
    size_t ss_off   = alloc(256 * 4);
    size_t bs_off   = alloc(512 * 4);
    size_t wp1_off  = alloc(32768 * 2);
    size_t wp2_off  = alloc(32768 * 2);

    if (ws_size < off) {
        diag_k<<<1, 64, 0, stream>>>(out, 1000.f + (float)(ws_size >> 20));
        return;
    }

    ushort_t* A = (ushort_t*)(ws + reg1_off);       // chain1 x_prev (V x 256)
    ushort_t* Bb = A + (size_t)V * 256;             // chain1 x_cur  (V x 256)
    ushort_t* C = (ushort_t*)(ws + reg1_off);       // chain2 buffer (V x 512)
    ushort_t* rb = (ushort_t*)(ws + rb_off);        // h / chain2    (V x 512)
    int* rowptr = (int*)(ws + rp_off);
    int* cursor = (int*)(ws + cur_off);             // doubles as counts
    int2* edges = (int2*)(ws + ed_off);
    float* stats = (float*)(ws + st_off);
    float* ss = (float*)(ws + ss_off);
    int* bsums = (int*)(ws + bs_off);
    ushort_t* wp1 = (ushort_t*)(ws + wp1_off);
    ushort_t* wp2 = (ushort_t*)(ws + wp2_off);

    const int NB = (V + 255) / 256;  // 391
    const ushort_t* nullu = (const ushort_t*)nullptr;

    hipMemsetAsync(cursor, 0, (size_t)V * 4, stream);
    hipMemsetAsync(stats, 0, 256 * 4, stream);

    pack_x0_k<<<dim3(V / 32, 8), 256, 0, stream>>>(x, A);
    prep_w_k<<<256, 256, 0, stream>>>(w1, w2, wp1, wp2);
    hist_k<<<NNZ / 256, 256, 0, stream>>>(lap_rows, cursor);
    scan1_k<<<NB, 256, 0, stream>>>(cursor, bsums);
    scan2_k<<<1, 512, 0, stream>>>(bsums, NB);
    scan3_k<<<NB, 256, 0, stream>>>(cursor, bsums, rowptr, cursor);
    scatter_k<<<NNZ / 256, 256, 0, stream>>>(lap_rows, lap_cols, lap_vals, cursor, edges);

    dim3 g1((V + 63) / 64, 4);    // 1563 x 4
    dim3 g2((V + 127) / 128, 4);  // 782 x 4

    // ---- Chain 1 (F=256) ----
    spmm_k<256><<<V / 2, 256, 0, stream>>>(rowptr, edges, A, nullu, ss, 0, 0, 1.f, 0.f, Bb);   // x1 = L x0
    gemm1_mfma<<<g1, 256, 0, stream>>>(A, Bb, wp1, b1, rb, stats, 1, 0);                        // rb = x0 W0 + x1 W1
    spmm_k<256><<<V / 2, 256, 0, stream>>>(rowptr, edges, Bb, A, ss, 0, 0, 2.f, -1.f, A);      // x2 = 2Lx1 - x0
    spmm_k<256><<<V / 2, 256, 0, stream>>>(rowptr, edges, A, Bb, ss, 0, 0, 2.f, -1.f, Bb);     // x3 = 2Lx2 - x1
    gemm1_mfma<<<g1, 256, 0, stream>>>(A, Bb, wp1 + 16384, b1, rb, stats, 0, 1);               // rb += x2 W2 + x3 W3; relu+stats

    finalize_k<<<1, 128, 0, stream>>>(stats, bn_gamma, bn_beta, ss);

    // ---- Chain 2 (F=512) ----
    spmm_k<512><<<V, 256, 0, stream>>>(rowptr, edges, rb, nullu, ss, 1, 0, 1.f, 0.f, C);       // y1 = L y0^
    gemm2_mfma<<<g2, 256, 0, stream>>>(rb, C, wp2, b2, x, ss, out, 1, 1, 0);                   // out = y0^ W0 + y1 W1
    spmm_k<512><<<V, 256, 0, stream>>>(rowptr, edges, C, rb, ss, 0, 1, 2.f, -1.f, rb);         // y2 = 2Ly1 - y0^
    spmm_k<512><<<V, 256, 0, stream>>>(rowptr, edges, rb, C, ss, 0, 0, 2.f, -1.f, C);          // y3 = 2Ly2 - y1
    gemm2_mfma<<<g2, 256, 0, stream>>>(rb, C, wp2 + 16384, b2, x, ss, out, 0, 0, 1);           // out += y2 W2 + y3 W3; +b2+res, relu
}

// Round 4
// 1995.294 us; speedup vs baseline: 2.9303x; 1.7355x over previous
//
#include <hip/hip_runtime.h>

#define V 100000
#define NNZ 1600000

typedef unsigned short ushort_t;
typedef unsigned int uint_t;
typedef __attribute__((ext_vector_type(4))) float f32x4;
typedef __attribute__((ext_vector_type(8))) short bf16x8;

__device__ __forceinline__ float bf2f(ushort_t u) {
    union { uint_t i; float f; } x; x.i = ((uint_t)u) << 16; return x.f;
}
__device__ __forceinline__ ushort_t f2bf(float f) {
    union { float f; uint_t i; } x; x.f = f;
    uint_t u = x.i;
    return (ushort_t)((u + 0x7fffu + ((u >> 16) & 1u)) >> 16);
}
__device__ __forceinline__ float blo(uint_t u) {
    union { uint_t i; float f; } x; x.i = u << 16; return x.f;
}
__device__ __forceinline__ float bhi(uint_t u) {
    union { uint_t i; float f; } x; x.i = u & 0xffff0000u; return x.f;
}

__global__ void diag_k(float* __restrict__ out, float code) {
    if (threadIdx.x == 0 && blockIdx.x == 0) out[0] = code;
}

// ---------------------------------------------------------------------------
// x (B,64,V) f32  ->  x0 (V, 256) bf16, x0[v][b*64+c] = x[b][c][v]
// ---------------------------------------------------------------------------
__global__ __launch_bounds__(256) void pack_x0_k(const float* __restrict__ x,
                                                 ushort_t* __restrict__ x0) {
    __shared__ float tile[32][33];
    int v0 = blockIdx.x * 32, j0 = blockIdx.y * 32;
    int tx = threadIdx.x & 31, ty = threadIdx.x >> 5;
    for (int jj = ty; jj < 32; jj += 8)
        tile[jj][tx] = x[(size_t)(j0 + jj) * V + v0 + tx];
    __syncthreads();
    for (int vv = ty; vv < 32; vv += 8)
        x0[(size_t)(v0 + vv) * 256 + j0 + tx] = f2bf(tile[tx][vv]);
}

// ---------------------------------------------------------------------------
// weights -> bf16, MFMA-B/A-fragment-swizzled
// ---------------------------------------------------------------------------
__global__ __launch_bounds__(256) void prep_w_k(const float* __restrict__ w1,
                                                const float* __restrict__ w2,
                                                ushort_t* __restrict__ wp1,
                                                ushort_t* __restrict__ wp2) {
    int idx = blockIdx.x * 256 + threadIdx.x;
    if (idx < 32768) {
        int f = idx;
        int j = f & 7, ch = (f >> 3) & 127, q = (f >> 10) & 3, kb = (f >> 12) & 3, L = (f >> 14) & 1;
        int k = kb * 32 + q * 8 + j;
        int t = L * 2 + (k >> 6), i = k & 63;
        wp1[idx] = f2bf(w1[((size_t)t * 64 + i) * 128 + ch]);
    } else {
        int f = idx - 32768;
        int j = f & 7, o = (f >> 3) & 63, q = (f >> 9) & 3, kb = (f >> 11) & 7, L = (f >> 14) & 1;
        int k = kb * 32 + q * 8 + j;
        int t = L * 2 + (k >> 7), ch = k & 127;
        wp2[f] = f2bf(w2[((size_t)t * 128 + ch) * 64 + o]);
    }
}

// ---------------------------------------------------------------------------
// CSR build
// ---------------------------------------------------------------------------
__global__ __launch_bounds__(256) void hist_k(const int* __restrict__ rows,
                                              int* __restrict__ counts) {
    int e = blockIdx.x * 256 + threadIdx.x;
    atomicAdd(&counts[rows[e]], 1);
}

__global__ __launch_bounds__(256) void scan1_k(const int* __restrict__ counts,
                                               int* __restrict__ bsums) {
    __shared__ int sd[256];
    int t = threadIdx.x;
    int v = blockIdx.x * 256 + t;
    sd[t] = (v < V) ? counts[v] : 0;
    __syncthreads();
    for (int s = 128; s > 0; s >>= 1) {
        if (t < s) sd[t] += sd[t + s];
        __syncthreads();
    }
    if (t == 0) bsums[blockIdx.x] = sd[0];
}

__global__ __launch_bounds__(512) void scan2_k(int* __restrict__ bsums, int nb) {
    __shared__ int sd[512];
    int t = threadIdx.x;
    int v = (t < nb) ? bsums[t] : 0;
    sd[t] = v;
    __syncthreads();
    for (int off = 1; off < 512; off <<= 1) {
        int a = (t >= off) ? sd[t - off] : 0;
        __syncthreads();
        sd[t] += a;
        __syncthreads();
    }
    if (t < nb) bsums[t] = sd[t] - v;  // exclusive
}

__global__ __launch_bounds__(256) void scan3_k(const int* __restrict__ counts,
                                               const int* __restrict__ bsums,
                                               int* __restrict__ rowptr,
                                               int* __restrict__ cursor) {
    __shared__ int sd[256];
    int t = threadIdx.x;
    int v = blockIdx.x * 256 + t;
    int c = (v < V) ? counts[v] : 0;
    sd[t] = c;
    __syncthreads();
    for (int off = 1; off < 256; off <<= 1) {
        int a = (t >= off) ? sd[t - off] : 0;
        __syncthreads();
        sd[t] += a;
        __syncthreads();
    }
    if (v < V) {
        int start = bsums[blockIdx.x] + sd[t] - c;
        rowptr[v] = start;
        cursor[v] = start;
    }
    if (v == 0) rowptr[V] = NNZ;
}

__global__ __launch_bounds__(256) void scatter_k(const int* __restrict__ rows,
                                                 const int* __restrict__ cols,
                                                 const float* __restrict__ vals,
                                                 int* __restrict__ cursor,
                                                 int2* __restrict__ edges) {
    int e = blockIdx.x * 256 + threadIdx.x;
    int r = rows[e];
    int pos = atomicAdd(&cursor[r], 1);
    edges[pos] = make_int2(cols[e], __float_as_int(vals[e]));
}

// ---------------------------------------------------------------------------
// SpMM (one wave per row): out[v][:] = alpha * sum_e val_e * nY(y[col_e][:])
//                                      + beta * nZ(z[v][:])
// Lane owns F/64 features; per edge one dwordx4/x2 gather; edges unrolled x4.
// out may alias z. NY: BN affine on gathered y (template for clean codegen).
// ---------------------------------------------------------------------------
template <int F, int NY>
__global__ __launch_bounds__(256) void spmm_wave(const int* __restrict__ rowptr,
                                                 const int2* __restrict__ edges,
                                                 const ushort_t* __restrict__ y,
                                                 const ushort_t* __restrict__ z,
                                                 const float* __restrict__ ss,
                                                 int normZ, float alpha, float beta,
                                                 ushort_t* __restrict__ out) {
    constexpr int EPL = F / 64;   // bf16 per lane: 4 (F=256) or 8 (F=512)
    constexpr int NU = EPL / 2;   // packed uints per lane
    int v = (blockIdx.x * 256 + threadIdx.x) >> 6;
    if (v >= V) return;
    int l = threadIdx.x & 63;
    int fo = l * EPL;
    const ushort_t* yl = y + fo;

    float sc[EPL], sh[EPL];
    if (NY) {
#pragma unroll
        for (int j = 0; j < EPL; ++j) {
            int c = (fo + j) & 127;
            sc[j] = ss[c];
            sh[j] = ss[128 + c];
        }
    }
    float acc[EPL];
#pragma unroll
    for (int j = 0; j < EPL; ++j) acc[j] = 0.f;

    auto loadU = [&](int col, uint_t* u) {
        const ushort_t* p = yl + (size_t)col * F;
        if (F == 512) {
            uint4 t = *(const uint4*)p;
            u[0] = t.x; u[1] = t.y; u[2] = t.z; u[3] = t.w;
        } else {
            uint2 t = *(const uint2*)p;
            u[0] = t.x; u[1] = t.y;
        }
    };
    auto accum = [&](float w, const uint_t* u) {
#pragma unroll
        for (int j = 0; j < NU; ++j) {
            float lo = blo(u[j]), hi = bhi(u[j]);
            if (NY) {
                lo = lo * sc[2 * j] + sh[2 * j];
                hi = hi * sc[2 * j + 1] + sh[2 * j + 1];
            }
            acc[2 * j] += w * lo;
            acc[2 * j + 1] += w * hi;
        }
    };

    int e0 = rowptr[v], e1 = rowptr[v + 1];
    int e = e0;
    for (; e + 4 <= e1; e += 4) {
        int2 ed0 = edges[e], ed1 = edges[e + 1], ed2 = edges[e + 2], ed3 = edges[e + 3];
        uint_t u0[NU], u1[NU], u2[NU], u3[NU];
        loadU(ed0.x, u0);
        loadU(ed1.x, u1);
        loadU(ed2.x, u2);
        loadU(ed3.x, u3);
        accum(__int_as_float(ed0.y), u0);
        accum(__int_as_float(ed1.y), u1);
        accum(__int_as_float(ed2.y), u2);
        accum(__int_as_float(ed3.y), u3);
    }
    int rem = e1 - e;
    if (rem > 0) {
        int i1 = e + (rem > 1 ? 1 : 0), i2 = e + (rem > 2 ? 2 : 0);
        int2 ed0 = edges[e], ed1 = edges[i1], ed2 = edges[i2];
        uint_t u0[NU], u1[NU], u2[NU];
        loadU(ed0.x, u0);
        loadU(ed1.x, u1);
        loadU(ed2.x, u2);
        accum(__int_as_float(ed0.y), u0);
        accum(rem > 1 ? __int_as_float(ed1.y) : 0.f, u1);
        accum(rem > 2 ? __int_as_float(ed2.y) : 0.f, u2);
    }

    float r[EPL];
#pragma unroll
    for (int j = 0; j < EPL; ++j) r[j] = alpha * acc[j];
    if (z) {
        uint_t uz[NU];
        const ushort_t* p = z + (size_t)v * F + fo;
        if (F == 512) {
            uint4 t = *(const uint4*)p;
            uz[0] = t.x; uz[1] = t.y; uz[2] = t.z; uz[3] = t.w;
        } else {
            uint2 t = *(const uint2*)p;
            uz[0] = t.x; uz[1] = t.y;
        }
#pragma unroll
        for (int j = 0; j < NU; ++j) {
            float lo = blo(uz[j]), hi = bhi(uz[j]);
            if (normZ) {
                int c0 = (fo + 2 * j) & 127;
                lo = lo * ss[c0] + ss[128 + c0];
                hi = hi * ss[c0 + 1] + ss[128 + c0 + 1];
            }
            r[2 * j] += beta * lo;
            r[2 * j + 1] += beta * hi;
        }
    }
    uint_t up[NU];
#pragma unroll
    for (int j = 0; j < NU; ++j)
        up[j] = (uint_t)f2bf(r[2 * j]) | ((uint_t)f2bf(r[2 * j + 1]) << 16);
    ushort_t* po = out + (size_t)v * F + fo;
    if (F == 512)
        *(uint4*)po = make_uint4(up[0], up[1], up[2], up[3]);
    else
        *(uint2*)po = make_uint2(up[0], up[1]);
}

// ---------------------------------------------------------------------------
// GEMM1 (MFMA): rb[v][b*128+ch] (+)= t0[v][b*64+i]*W(k0) + t1[v][b*64+i]*W(k0+1)
// ---------------------------------------------------------------------------
__global__ __launch_bounds__(256) void gemm1_mfma(const ushort_t* __restrict__ t0,
                                                  const ushort_t* __restrict__ t1,
                                                  const ushort_t* __restrict__ wp,
                                                  const float* __restrict__ b1,
                                                  ushort_t* __restrict__ rb,
                                                  float* __restrict__ stats,
                                                  int first, int last) {
    __shared__ float s_sum[128];
    __shared__ float s_sq[128];
    int tid = threadIdx.x;
    int l = tid & 63, w = tid >> 6;
    int q = l >> 4, n16 = l & 15;
    int b = blockIdx.y;
    int v0 = blockIdx.x * 64;
    if (last && tid < 128) { s_sum[tid] = 0.f; s_sq[tid] = 0.f; }
    int vrow = v0 + w * 16 + n16;
    int vc = vrow < V ? vrow : V - 1;

    f32x4 acc[8];
#pragma unroll
    for (int ct = 0; ct < 8; ++ct) acc[ct] = (f32x4){0.f, 0.f, 0.f, 0.f};

#pragma unroll
    for (int kb = 0; kb < 4; ++kb) {
        const ushort_t* tab = (kb < 2) ? t0 : t1;
        bf16x8 a = *(const bf16x8*)(tab + (size_t)vc * 256 + b * 64 + (kb & 1) * 32 + q * 8);
#pragma unroll
        for (int ct = 0; ct < 8; ++ct) {
            bf16x8 bf = *(const bf16x8*)(wp + (size_t)(((kb * 4 + q) * 128) + ct * 16 + n16) * 8);
            acc[ct] = __builtin_amdgcn_mfma_f32_16x16x32_bf16(a, bf, acc[ct], 0, 0, 0);
        }
    }

    float ls[8], lq[8];
#pragma unroll
    for (int ct = 0; ct < 8; ++ct) {
        ls[ct] = 0.f; lq[ct] = 0.f;
        float bc = last ? b1[ct * 16 + n16] : 0.f;
#pragma unroll
        for (int r = 0; r < 4; ++r) {
            int v = v0 + w * 16 + q * 4 + r;
            bool valid = v < V;
            float val = acc[ct][r];
            ushort_t* p = rb + (size_t)(valid ? v : 0) * 512 + b * 128 + ct * 16 + n16;
            if (!first && valid) val += bf2f(*p);
            if (last) {
                val = fmaxf(val + bc, 0.f);
                if (valid) { ls[ct] += val; lq[ct] += val * val; }
            }
            if (valid) *p = f2bf(val);
        }
    }
    if (last) {
        __syncthreads();
#pragma unroll
        for (int ct = 0; ct < 8; ++ct) {
            atomicAdd(&s_sum[ct * 16 + n16], ls[ct]);
            atomicAdd(&s_sq[ct * 16 + n16], lq[ct]);
        }
        __syncthreads();
        if (tid < 128) {
            atomicAdd(&stats[tid], s_sum[tid]);
            atomicAdd(&stats[128 + tid], s_sq[tid]);
        }
    }
}

__global__ void finalize_k(const float* __restrict__ stats,
                           const float* __restrict__ gamma,
                           const float* __restrict__ beta,
                           float* __restrict__ ss) {
    int c = threadIdx.x;  // 128 threads
    float n = (float)(4 * V);
    float mean = stats[c] / n;
    float var = stats[128 + c] / n - mean * mean;
    float inv = rsqrtf(var + 1e-5f);
    float sc = gamma[c] * inv;
    ss[c] = sc;
    ss[128 + c] = beta[c] - mean * sc;
}

// ---------------------------------------------------------------------------
// GEMM2 (MFMA): out[b][o][v] (+)= sum_ch W2(k)[ch][o]*Y(k)[v][b*128+ch], 2 terms
// ---------------------------------------------------------------------------
__global__ __launch_bounds__(256) void gemm2_mfma(const ushort_t* __restrict__ t0,
                                                  const ushort_t* __restrict__ t1,
                                                  const ushort_t* __restrict__ wp,
                                                  const float* __restrict__ b2,
                                                  const float* __restrict__ xres,
                                                  const float* __restrict__ ss,
                                                  float* __restrict__ out,
                                                  int norm0, int first, int last) {
    __shared__ float s_ss[256];
    int tid = threadIdx.x;
    s_ss[tid] = ss[tid];
    __syncthreads();
    int l = tid & 63, w = tid >> 6;
    int q = l >> 4, n16 = l & 15;
    int b = blockIdx.y;
    int v0 = blockIdx.x * 128;

    f32x4 acc[4][2];
#pragma unroll
    for (int rt = 0; rt < 4; ++rt)
#pragma unroll
        for (int c = 0; c < 2; ++c) acc[rt][c] = (f32x4){0.f, 0.f, 0.f, 0.f};

    int vcol[2];
#pragma unroll
    for (int c = 0; c < 2; ++c) {
        int v = v0 + (w * 2 + c) * 16 + n16;
        vcol[c] = v < V ? v : V - 1;
    }

#pragma unroll
    for (int kb = 0; kb < 8; ++kb) {
        const ushort_t* tab = (kb < 4) ? t0 : t1;
        int nrm = (kb < 4) ? norm0 : 0;
        int chl = (kb & 3) * 32 + q * 8;
        bf16x8 bfr[2];
#pragma unroll
        for (int c = 0; c < 2; ++c) {
            bf16x8 t = *(const bf16x8*)(tab + (size_t)vcol[c] * 512 + b * 128 + chl);
            if (nrm) {
#pragma unroll
                for (int j = 0; j < 8; ++j) {
                    float f = bf2f((ushort_t)t[j]);
                    f = f * s_ss[chl + j] + s_ss[128 + chl + j];
                    t[j] = (short)f2bf(f);
                }
            }
            bfr[c] = t;
        }
#pragma unroll
        for (int rt = 0; rt < 4; ++rt) {
            bf16x8 af = *(const bf16x8*)(wp + (size_t)(((kb * 4 + q) * 64) + rt * 16 + n16) * 8);
#pragma unroll
            for (int c = 0; c < 2; ++c)
                acc[rt][c] = __builtin_amdgcn_mfma_f32_16x16x32_bf16(af, bfr[c], acc[rt][c], 0, 0, 0);
        }
    }

#pragma unroll
    for (int rt = 0; rt < 4; ++rt)
#pragma unroll
        for (int c = 0; c < 2; ++c) {
            int v = v0 + (w * 2 + c) * 16 + n16;
            bool valid = v < V;
#pragma unroll
            for (int r = 0; r < 4; ++r) {
                int o = rt * 16 + q * 4 + r;
                size_t idx = (size_t)(b * 64 + o) * V + v;
                float val = acc[rt][c][r];
                if (valid) {
                    if (!first) val += out[idx];
                    if (last) val = fmaxf(val + b2[o] + xres[idx], 0.f);
                    out[idx] = val;
                }
            }
        }
}

// ---------------------------------------------------------------------------
extern "C" void kernel_launch(void* const* d_in, const int* in_sizes, int n_in,
                              void* d_out, int out_size, void* d_ws, size_t ws_size,
                              hipStream_t stream) {
    const float* x = (const float*)d_in[0];
    const int* lap_rows = (const int*)d_in[1];
    const int* lap_cols = (const int*)d_in[2];
    const float* lap_vals = (const float*)d_in[3];
    const float* w1 = (const float*)d_in[4];
    const float* b1 = (const float*)d_in[5];
    const float* bn_gamma = (const float*)d_in[6];
    const float* bn_beta = (const float*)d_in[7];
    const float* w2 = (const float*)d_in[8];
    const float* b2 = (const float*)d_in[9];
    float* out = (float*)d_out;

    char* ws = (char*)d_ws;
    size_t off = 0;
    auto alloc = [&](size_t bytes) {
        size_t r = off;
        off = (off + bytes + 255) & ~(size_t)255;
        return r;
    };
    size_t reg1_off = alloc((size_t)V * 512 * 2);  // chain1 A+B / chain2 C (102.4 MB)
    size_t rb_off   = alloc((size_t)V * 512 * 2);  // h / chain2 ping-pong (102.4 MB)
    size_t rp_off   = alloc((size_t)(V + 1) * 4);
    size_t cur_off  = alloc((size_t)V * 4);
    size_t ed_off   = alloc((size_t)NNZ * 8);
    size_t st_off   = alloc(256 * 4);
    size_t ss_off   = alloc(256 * 4);
    size_t bs_off   = alloc(512 * 4);
    size_t wp1_off  = alloc(32768 * 2);
    size_t wp2_off  = alloc(32768 * 2);

    if (ws_size < off) {
        diag_k<<<1, 64, 0, stream>>>(out, 1000.f + (float)(ws_size >> 20));
        return;
    }

    ushort_t* A = (ushort_t*)(ws + reg1_off);       // chain1 x_prev (V x 256)
    ushort_t* Bb = A + (size_t)V * 256;             // chain1 x_cur  (V x 256)
    ushort_t* C = (ushort_t*)(ws + reg1_off);       // chain2 buffer (V x 512)
    ushort_t* rb = (ushort_t*)(ws + rb_off);        // h / chain2    (V x 512)
    int* rowptr = (int*)(ws + rp_off);
    int* cursor = (int*)(ws + cur_off);             // doubles as counts
    int2* edges = (int2*)(ws + ed_off);
    float* stats = (float*)(ws + st_off);
    float* ss = (float*)(ws + ss_off);
    int* bsums = (int*)(ws + bs_off);
    ushort_t* wp1 = (ushort_t*)(ws + wp1_off);
    ushort_t* wp2 = (ushort_t*)(ws + wp2_off);

    const int NB = (V + 255) / 256;  // 391
    const int SG = (V + 3) / 4;      // spmm grid: 1 wave per row, 4 rows/block
    const ushort_t* nullu = (const ushort_t*)nullptr;

    hipMemsetAsync(cursor, 0, (size_t)V * 4, stream);
    hipMemsetAsync(stats, 0, 256 * 4, stream);

    pack_x0_k<<<dim3(V / 32, 8), 256, 0, stream>>>(x, A);
    prep_w_k<<<256, 256, 0, stream>>>(w1, w2, wp1, wp2);
    hist_k<<<NNZ / 256, 256, 0, stream>>>(lap_rows, cursor);
    scan1_k<<<NB, 256, 0, stream>>>(cursor, bsums);
    scan2_k<<<1, 512, 0, stream>>>(bsums, NB);
    scan3_k<<<NB, 256, 0, stream>>>(cursor, bsums, rowptr, cursor);
    scatter_k<<<NNZ / 256, 256, 0, stream>>>(lap_rows, lap_cols, lap_vals, cursor, edges);

    dim3 g1((V + 63) / 64, 4);    // 1563 x 4
    dim3 g2((V + 127) / 128, 4);  // 782 x 4

    // ---- Chain 1 (F=256) ----
    spmm_wave<256, 0><<<SG, 256, 0, stream>>>(rowptr, edges, A, nullu, ss, 0, 1.f, 0.f, Bb);  // x1 = L x0
    gemm1_mfma<<<g1, 256, 0, stream>>>(A, Bb, wp1, b1, rb, stats, 1, 0);                      // rb = x0 W0 + x1 W1
    spmm_wave<256, 0><<<SG, 256, 0, stream>>>(rowptr, edges, Bb, A, ss, 0, 2.f, -1.f, A);     // x2 = 2Lx1 - x0
    spmm_wave<256, 0><<<SG, 256, 0, stream>>>(rowptr, edges, A, Bb, ss, 0, 2.f, -1.f, Bb);    // x3 = 2Lx2 - x1
    gemm1_mfma<<<g1, 256, 0, stream>>>(A, Bb, wp1 + 16384, b1, rb, stats, 0, 1);              // rb += x2 W2 + x3 W3

    finalize_k<<<1, 128, 0, stream>>>(stats, bn_gamma, bn_beta, ss);

    // ---- Chain 2 (F=512) ----
    spmm_wave<512, 1><<<SG, 256, 0, stream>>>(rowptr, edges, rb, nullu, ss, 0, 1.f, 0.f, C);  // y1 = L y0^
    gemm2_mfma<<<g2, 256, 0, stream>>>(rb, C, wp2, b2, x, ss, out, 1, 1, 0);                  // out = y0^ W0 + y1 W1
    spmm_wave<512, 0><<<SG, 256, 0, stream>>>(rowptr, edges, C, rb, ss, 1, 2.f, -1.f, rb);    // y2 = 2Ly1 - y0^
    spmm_wave<512, 0><<<SG, 256, 0, stream>>>(rowptr, edges, rb, C, ss, 0, 2.f, -1.f, C);     // y3 = 2Ly2 - y1
    gemm2_mfma<<<g2, 256, 0, stream>>>(rb, C, wp2 + 16384, b2, x, ss, out, 0, 0, 1);          // out += y2 W2 + y3 W3
}

// Round 5
// 1635.275 us; speedup vs baseline: 3.5755x; 1.2202x over previous
//
#include <hip/hip_runtime.h>

#define V 100000
#define NNZ 1600000

typedef unsigned short ushort_t;
typedef unsigned int uint_t;
typedef __attribute__((ext_vector_type(4))) float f32x4;
typedef __attribute__((ext_vector_type(8))) short bf16x8;

__device__ __forceinline__ float bf2f(ushort_t u) {
    union { uint_t i; float f; } x; x.i = ((uint_t)u) << 16; return x.f;
}
__device__ __forceinline__ ushort_t f2bf(float f) {
    union { float f; uint_t i; } x; x.f = f;
    uint_t u = x.i;
    return (ushort_t)((u + 0x7fffu + ((u >> 16) & 1u)) >> 16);
}
__device__ __forceinline__ float blo(uint_t u) {
    union { uint_t i; float f; } x; x.i = u << 16; return x.f;
}
__device__ __forceinline__ float bhi(uint_t u) {
    union { uint_t i; float f; } x; x.i = u & 0xffff0000u; return x.f;
}

__global__ void diag_k(float* __restrict__ out, float code) {
    if (threadIdx.x == 0 && blockIdx.x == 0) out[0] = code;
}

// ---------------------------------------------------------------------------
// x (B,64,V) f32  ->  x0 (V, 256) bf16, x0[v][b*64+c] = x[b][c][v]
// ---------------------------------------------------------------------------
__global__ __launch_bounds__(256) void pack_x0_k(const float* __restrict__ x,
                                                 ushort_t* __restrict__ x0) {
    __shared__ float tile[32][33];
    int v0 = blockIdx.x * 32, j0 = blockIdx.y * 32;
    int tx = threadIdx.x & 31, ty = threadIdx.x >> 5;
    for (int jj = ty; jj < 32; jj += 8)
        tile[jj][tx] = x[(size_t)(j0 + jj) * V + v0 + tx];
    __syncthreads();
    for (int vv = ty; vv < 32; vv += 8)
        x0[(size_t)(v0 + vv) * 256 + j0 + tx] = f2bf(tile[tx][vv]);
}

// ---------------------------------------------------------------------------
// weights -> bf16, MFMA-fragment-swizzled
// wp1[L][kb(4)][q(4)][ch(128)][j(8)] = w1[L*2+(k>>6)][k&63][ch], k=kb*32+q*8+j
// wp2[t(4)][kb(4)][q(4)][o(64)][j(8)] = w2[t][k][o],            k=kb*32+q*8+j
// ---------------------------------------------------------------------------
__global__ __launch_bounds__(256) void prep_w_k(const float* __restrict__ w1,
                                                const float* __restrict__ w2,
                                                ushort_t* __restrict__ wp1,
                                                ushort_t* __restrict__ wp2) {
    int idx = blockIdx.x * 256 + threadIdx.x;
    if (idx < 32768) {
        int f = idx;
        int j = f & 7, ch = (f >> 3) & 127, q = (f >> 10) & 3, kb = (f >> 12) & 3, L = (f >> 14) & 1;
        int k = kb * 32 + q * 8 + j;
        int t = L * 2 + (k >> 6), i = k & 63;
        wp1[idx] = f2bf(w1[((size_t)t * 64 + i) * 128 + ch]);
    } else {
        int f = idx - 32768;
        int j = f & 7, o = (f >> 3) & 63, q = (f >> 9) & 3, kb = (f >> 11) & 3, t = (f >> 13) & 3;
        int k = kb * 32 + q * 8 + j;
        wp2[f] = f2bf(w2[((size_t)t * 128 + k) * 64 + o]);
    }
}

// ---------------------------------------------------------------------------
// CSR build
// ---------------------------------------------------------------------------
__global__ __launch_bounds__(256) void hist_k(const int* __restrict__ rows,
                                              int* __restrict__ counts) {
    int e = blockIdx.x * 256 + threadIdx.x;
    atomicAdd(&counts[rows[e]], 1);
}

__global__ __launch_bounds__(256) void scan1_k(const int* __restrict__ counts,
                                               int* __restrict__ bsums) {
    __shared__ int sd[256];
    int t = threadIdx.x;
    int v = blockIdx.x * 256 + t;
    sd[t] = (v < V) ? counts[v] : 0;
    __syncthreads();
    for (int s = 128; s > 0; s >>= 1) {
        if (t < s) sd[t] += sd[t + s];
        __syncthreads();
    }
    if (t == 0) bsums[blockIdx.x] = sd[0];
}

__global__ __launch_bounds__(512) void scan2_k(int* __restrict__ bsums, int nb) {
    __shared__ int sd[512];
    int t = threadIdx.x;
    int v = (t < nb) ? bsums[t] : 0;
    sd[t] = v;
    __syncthreads();
    for (int off = 1; off < 512; off <<= 1) {
        int a = (t >= off) ? sd[t - off] : 0;
        __syncthreads();
        sd[t] += a;
        __syncthreads();
    }
    if (t < nb) bsums[t] = sd[t] - v;  // exclusive
}

__global__ __launch_bounds__(256) void scan3_k(const int* __restrict__ counts,
                                               const int* __restrict__ bsums,
                                               int* __restrict__ rowptr,
                                               int* __restrict__ cursor) {
    __shared__ int sd[256];
    int t = threadIdx.x;
    int v = blockIdx.x * 256 + t;
    int c = (v < V) ? counts[v] : 0;
    sd[t] = c;
    __syncthreads();
    for (int off = 1; off < 256; off <<= 1) {
        int a = (t >= off) ? sd[t - off] : 0;
        __syncthreads();
        sd[t] += a;
        __syncthreads();
    }
    if (v < V) {
        int start = bsums[blockIdx.x] + sd[t] - c;
        rowptr[v] = start;
        cursor[v] = start;
    }
    if (v == 0) rowptr[V] = NNZ;
}

__global__ __launch_bounds__(256) void scatter_k(const int* __restrict__ rows,
                                                 const int* __restrict__ cols,
                                                 const float* __restrict__ vals,
                                                 int* __restrict__ cursor,
                                                 int2* __restrict__ edges) {
    int e = blockIdx.x * 256 + threadIdx.x;
    int r = rows[e];
    int pos = atomicAdd(&cursor[r], 1);
    edges[pos] = make_int2(cols[e], __float_as_int(vals[e]));
}

// ---------------------------------------------------------------------------
// SpMM F=256, one wave per row: out[v][:] = alpha*sum_e val_e*y[col_e][:]
//                                           + beta*z[v][:]
// Lane owns 4 bf16 (8B gather). 8-deep unrolled main loop + masked-4 tails.
// out may alias z.
// ---------------------------------------------------------------------------
__global__ __launch_bounds__(256) void spmm_wave(const int* __restrict__ rowptr,
                                                 const int2* __restrict__ edges,
                                                 const ushort_t* __restrict__ y,
                                                 const ushort_t* __restrict__ z,
                                                 float alpha, float beta,
                                                 ushort_t* __restrict__ out) {
    int v = (blockIdx.x * 256 + threadIdx.x) >> 6;
    if (v >= V) return;
    int l = threadIdx.x & 63;
    const ushort_t* yl = y + l * 4;

    float a0 = 0.f, a1 = 0.f, a2 = 0.f, a3 = 0.f;
    int e0 = rowptr[v], e1 = rowptr[v + 1];
    int e = e0;
    for (; e + 8 <= e1; e += 8) {
        int2 ed[8];
#pragma unroll
        for (int i = 0; i < 8; ++i) ed[i] = edges[e + i];
        uint2 u[8];
#pragma unroll
        for (int i = 0; i < 8; ++i) u[i] = *(const uint2*)(yl + (size_t)ed[i].x * 256);
#pragma unroll
        for (int i = 0; i < 8; ++i) {
            float wv = __int_as_float(ed[i].y);
            a0 += wv * blo(u[i].x);
            a1 += wv * bhi(u[i].x);
            a2 += wv * blo(u[i].y);
            a3 += wv * bhi(u[i].y);
        }
    }
    auto masked4 = [&](int base, int cnt) {
        int2 ed[4];
#pragma unroll
        for (int i = 0; i < 4; ++i) ed[i] = edges[i < cnt ? base + i : e0];
        uint2 u[4];
#pragma unroll
        for (int i = 0; i < 4; ++i) u[i] = *(const uint2*)(yl + (size_t)ed[i].x * 256);
#pragma unroll
        for (int i = 0; i < 4; ++i) {
            float wv = (i < cnt) ? __int_as_float(ed[i].y) : 0.f;
            a0 += wv * blo(u[i].x);
            a1 += wv * bhi(u[i].x);
            a2 += wv * blo(u[i].y);
            a3 += wv * bhi(u[i].y);
        }
    };
    int rem = e1 - e;
    if (rem > 0) masked4(e, rem > 4 ? 4 : rem);
    if (rem > 4) masked4(e + 4, rem - 4);

    float r0 = alpha * a0, r1 = alpha * a1, r2 = alpha * a2, r3 = alpha * a3;
    if (z) {
        uint2 t = *(const uint2*)(z + (size_t)v * 256 + l * 4);
        r0 += beta * blo(t.x);
        r1 += beta * bhi(t.x);
        r2 += beta * blo(t.y);
        r3 += beta * bhi(t.y);
    }
    uint2 st;
    st.x = (uint_t)f2bf(r0) | ((uint_t)f2bf(r1) << 16);
    st.y = (uint_t)f2bf(r2) | ((uint_t)f2bf(r3) << 16);
    *(uint2*)(out + (size_t)v * 256 + l * 4) = st;
}

// ---------------------------------------------------------------------------
// GEMM1 (MFMA): rb[v][b*128+ch] (+)= t0[v][b*64+i]*W(k0) + t1[v][b*64+i]*W(k0+1)
// ---------------------------------------------------------------------------
__global__ __launch_bounds__(256) void gemm1_mfma(const ushort_t* __restrict__ t0,
                                                  const ushort_t* __restrict__ t1,
                                                  const ushort_t* __restrict__ wp,
                                                  const float* __restrict__ b1,
                                                  ushort_t* __restrict__ rb,
                                                  float* __restrict__ stats,
                                                  int first, int last) {
    __shared__ float s_sum[128];
    __shared__ float s_sq[128];
    int tid = threadIdx.x;
    int l = tid & 63, w = tid >> 6;
    int q = l >> 4, n16 = l & 15;
    int b = blockIdx.y;
    int v0 = blockIdx.x * 64;
    if (last && tid < 128) { s_sum[tid] = 0.f; s_sq[tid] = 0.f; }
    int vrow = v0 + w * 16 + n16;
    int vc = vrow < V ? vrow : V - 1;

    f32x4 acc[8];
#pragma unroll
    for (int ct = 0; ct < 8; ++ct) acc[ct] = (f32x4){0.f, 0.f, 0.f, 0.f};

#pragma unroll
    for (int kb = 0; kb < 4; ++kb) {
        const ushort_t* tab = (kb < 2) ? t0 : t1;
        bf16x8 a = *(const bf16x8*)(tab + (size_t)vc * 256 + b * 64 + (kb & 1) * 32 + q * 8);
#pragma unroll
        for (int ct = 0; ct < 8; ++ct) {
            bf16x8 bf = *(const bf16x8*)(wp + (size_t)(((kb * 4 + q) * 128) + ct * 16 + n16) * 8);
            acc[ct] = __builtin_amdgcn_mfma_f32_16x16x32_bf16(a, bf, acc[ct], 0, 0, 0);
        }
    }

    float ls[8], lq[8];
#pragma unroll
    for (int ct = 0; ct < 8; ++ct) {
        ls[ct] = 0.f; lq[ct] = 0.f;
        float bc = last ? b1[ct * 16 + n16] : 0.f;
#pragma unroll
        for (int r = 0; r < 4; ++r) {
            int v = v0 + w * 16 + q * 4 + r;
            bool valid = v < V;
            float val = acc[ct][r];
            ushort_t* p = rb + (size_t)(valid ? v : 0) * 512 + b * 128 + ct * 16 + n16;
            if (!first && valid) val += bf2f(*p);
            if (last) {
                val = fmaxf(val + bc, 0.f);
                if (valid) { ls[ct] += val; lq[ct] += val * val; }
            }
            if (valid) *p = f2bf(val);
        }
    }
    if (last) {
        __syncthreads();
#pragma unroll
        for (int ct = 0; ct < 8; ++ct) {
            atomicAdd(&s_sum[ct * 16 + n16], ls[ct]);
            atomicAdd(&s_sq[ct * 16 + n16], lq[ct]);
        }
        __syncthreads();
        if (tid < 128) {
            atomicAdd(&stats[tid], s_sum[tid]);
            atomicAdd(&stats[128 + tid], s_sq[tid]);
        }
    }
}

__global__ void finalize_k(const float* __restrict__ stats,
                           const float* __restrict__ gamma,
                           const float* __restrict__ beta,
                           float* __restrict__ ss) {
    int c = threadIdx.x;  // 128 threads
    float n = (float)(4 * V);
    float mean = stats[c] / n;
    float var = stats[128 + c] / n - mean * mean;
    float inv = rsqrtf(var + 1e-5f);
    float sc = gamma[c] * inv;
    ss[c] = sc;
    ss[128 + c] = beta[c] - mean * sc;
}

// ---------------------------------------------------------------------------
// gemmC: P[v][b*64+o] = nrm(rb)[v][b*128+:] . W_t[:, o]  (+ S[v][b*64+o])
// A = normalized yhat0 (m=v), B = wp (n=o), K=128. Block 64v x (4 batches).
// ---------------------------------------------------------------------------
__global__ __launch_bounds__(256) void gemmC_mfma(const ushort_t* __restrict__ rb,
                                                  const ushort_t* __restrict__ wp,
                                                  const ushort_t* __restrict__ S,
                                                  const float* __restrict__ ss,
                                                  ushort_t* __restrict__ P) {
    __shared__ float s_ss[256];
    int tid = threadIdx.x;
    s_ss[tid] = ss[tid];
    __syncthreads();
    int l = tid & 63, w = tid >> 6;
    int q = l >> 4, n16 = l & 15;
    int b = blockIdx.y;
    int v0 = blockIdx.x * 64;
    int vrow = v0 + w * 16 + n16;
    int vc = vrow < V ? vrow : V - 1;

    f32x4 acc[4];
#pragma unroll
    for (int ct = 0; ct < 4; ++ct) acc[ct] = (f32x4){0.f, 0.f, 0.f, 0.f};

#pragma unroll
    for (int kb = 0; kb < 4; ++kb) {
        int chl = kb * 32 + q * 8;
        bf16x8 a = *(const bf16x8*)(rb + (size_t)vc * 512 + b * 128 + chl);
#pragma unroll
        for (int j = 0; j < 8; ++j) {
            float f = bf2f((ushort_t)a[j]) * s_ss[chl + j] + s_ss[128 + chl + j];
            a[j] = (short)f2bf(f);
        }
#pragma unroll
        for (int ct = 0; ct < 4; ++ct) {
            bf16x8 bf = *(const bf16x8*)(wp + (size_t)(((kb * 4 + q) * 64) + ct * 16 + n16) * 8);
            acc[ct] = __builtin_amdgcn_mfma_f32_16x16x32_bf16(a, bf, acc[ct], 0, 0, 0);
        }
    }

#pragma unroll
    for (int ct = 0; ct < 4; ++ct) {
#pragma unroll
        for (int r = 0; r < 4; ++r) {
            int v = v0 + w * 16 + q * 4 + r;
            if (v < V) {
                size_t idx = (size_t)v * 256 + b * 64 + ct * 16 + n16;
                float val = acc[ct][r];
                if (S) val += bf2f(S[idx]);
                P[idx] = f2bf(val);
            }
        }
    }
}

// ---------------------------------------------------------------------------
// Final: out[b][o][v] = relu( W0[ch][o].nrm(rb)[v][b*128+ch] + Tb[v][b*64+o]
//                             + b2[o] + x[b][o][v] )
// A = W0 (m=o), B = normalized yhat0 (n=v), K=128. Block 64o x 128v x 4b.
// ---------------------------------------------------------------------------
__global__ __launch_bounds__(256) void gemm2_final(const ushort_t* __restrict__ rb,
                                                   const ushort_t* __restrict__ wp,
                                                   const ushort_t* __restrict__ Tb,
                                                   const float* __restrict__ b2,
                                                   const float* __restrict__ xres,
                                                   const float* __restrict__ ss,
                                                   float* __restrict__ out) {
    __shared__ float s_ss[256];
    int tid = threadIdx.x;
    s_ss[tid] = ss[tid];
    __syncthreads();
    int l = tid & 63, w = tid >> 6;
    int q = l >> 4, n16 = l & 15;
    int b = blockIdx.y;
    int v0 = blockIdx.x * 128;

    f32x4 acc[4][2];
#pragma unroll
    for (int rt = 0; rt < 4; ++rt)
#pragma unroll
        for (int c = 0; c < 2; ++c) acc[rt][c] = (f32x4){0.f, 0.f, 0.f, 0.f};

    int vcol[2];
#pragma unroll
    for (int c = 0; c < 2; ++c) {
        int v = v0 + (w * 2 + c) * 16 + n16;
        vcol[c] = v < V ? v : V - 1;
    }

#pragma unroll
    for (int kb = 0; kb < 4; ++kb) {
        int chl = kb * 32 + q * 8;
        bf16x8 bfr[2];
#pragma unroll
        for (int c = 0; c < 2; ++c) {
            bf16x8 t = *(const bf16x8*)(rb + (size_t)vcol[c] * 512 + b * 128 + chl);
#pragma unroll
            for (int j = 0; j < 8; ++j) {
                float f = bf2f((ushort_t)t[j]) * s_ss[chl + j] + s_ss[128 + chl + j];
                t[j] = (short)f2bf(f);
            }
            bfr[c] = t;
        }
#pragma unroll
        for (int rt = 0; rt < 4; ++rt) {
            bf16x8 af = *(const bf16x8*)(wp + (size_t)(((kb * 4 + q) * 64) + rt * 16 + n16) * 8);
#pragma unroll
            for (int c = 0; c < 2; ++c)
                acc[rt][c] = __builtin_amdgcn_mfma_f32_16x16x32_bf16(af, bfr[c], acc[rt][c], 0, 0, 0);
        }
    }

#pragma unroll
    for (int rt = 0; rt < 4; ++rt)
#pragma unroll
        for (int c = 0; c < 2; ++c) {
            int v = v0 + (w * 2 + c) * 16 + n16;
            bool valid = v < V;
#pragma unroll
            for (int r = 0; r < 4; ++r) {
                int o = rt * 16 + q * 4 + r;
                if (valid) {
                    size_t idx = (size_t)(b * 64 + o) * V + v;
                    float val = acc[rt][c][r] + bf2f(Tb[(size_t)v * 256 + b * 64 + o])
                              + b2[o] + xres[idx];
                    out[idx] = fmaxf(val, 0.f);
                }
            }
        }
}

// ---------------------------------------------------------------------------
extern "C" void kernel_launch(void* const* d_in, const int* in_sizes, int n_in,
                              void* d_out, int out_size, void* d_ws, size_t ws_size,
                              hipStream_t stream) {
    const float* x = (const float*)d_in[0];
    const int* lap_rows = (const int*)d_in[1];
    const int* lap_cols = (const int*)d_in[2];
    const float* lap_vals = (const float*)d_in[3];
    const float* w1 = (const float*)d_in[4];
    const float* b1 = (const float*)d_in[5];
    const float* bn_gamma = (const float*)d_in[6];
    const float* bn_beta = (const float*)d_in[7];
    const float* w2 = (const float*)d_in[8];
    const float* b2 = (const float*)d_in[9];
    float* out = (float*)d_out;

    char* ws = (char*)d_ws;
    size_t off = 0;
    auto alloc = [&](size_t bytes) {
        size_t r = off;
        off = (off + bytes + 255) & ~(size_t)255;
        return r;
    };
    size_t reg1_off = alloc((size_t)V * 512 * 2);  // slotA+slotB (102.4 MB)
    size_t rb_off   = alloc((size_t)V * 512 * 2);  // yhat0 = relu(h) (102.4 MB)
    size_t sc_off   = alloc((size_t)V * 256 * 2);  // slotC (51.2 MB)
    size_t rp_off   = alloc((size_t)(V + 1) * 4);
    size_t cur_off  = alloc((size_t)V * 4);
    size_t ed_off   = alloc((size_t)NNZ * 8);
    size_t st_off   = alloc(256 * 4);
    size_t ss_off   = alloc(256 * 4);
    size_t bs_off   = alloc(512 * 4);
    size_t wp1_off  = alloc(32768 * 2);
    size_t wp2_off  = alloc(32768 * 2);

    if (ws_size < off) {
        diag_k<<<1, 64, 0, stream>>>(out, 1000.f + (float)(ws_size >> 20));
        return;
    }

    ushort_t* slotA = (ushort_t*)(ws + reg1_off);   // V x 256
    ushort_t* slotB = slotA + (size_t)V * 256;      // V x 256
    ushort_t* slotC = (ushort_t*)(ws + sc_off);     // V x 256
    ushort_t* rb = (ushort_t*)(ws + rb_off);        // V x 512
    int* rowptr = (int*)(ws + rp_off);
    int* cursor = (int*)(ws + cur_off);             // doubles as counts
    int2* edges = (int2*)(ws + ed_off);
    float* stats = (float*)(ws + st_off);
    float* ss = (float*)(ws + ss_off);
    int* bsums = (int*)(ws + bs_off);
    ushort_t* wp1 = (ushort_t*)(ws + wp1_off);
    ushort_t* wp2 = (ushort_t*)(ws + wp2_off);

    const int NB = (V + 255) / 256;  // 391
    const int SG = (V + 3) / 4;      // spmm: 1 wave/row, 4 rows/block
    const ushort_t* nullu = (const ushort_t*)nullptr;

    hipMemsetAsync(cursor, 0, (size_t)V * 4, stream);
    hipMemsetAsync(stats, 0, 256 * 4, stream);

    pack_x0_k<<<dim3(V / 32, 8), 256, 0, stream>>>(x, slotA);
    prep_w_k<<<256, 256, 0, stream>>>(w1, w2, wp1, wp2);
    hist_k<<<NNZ / 256, 256, 0, stream>>>(lap_rows, cursor);
    scan1_k<<<NB, 256, 0, stream>>>(cursor, bsums);
    scan2_k<<<1, 512, 0, stream>>>(bsums, NB);
    scan3_k<<<NB, 256, 0, stream>>>(cursor, bsums, rowptr, cursor);
    scatter_k<<<NNZ / 256, 256, 0, stream>>>(lap_rows, lap_cols, lap_vals, cursor, edges);

    dim3 g1((V + 63) / 64, 4);    // gemm1 / gemmC
    dim3 g2((V + 127) / 128, 4);  // gemm2_final

    // ---- Chain 1 (forward recurrence, F=256) ----
    spmm_wave<<<SG, 256, 0, stream>>>(rowptr, edges, slotA, nullu, 1.f, 0.f, slotB);   // x1 = L x0
    gemm1_mfma<<<g1, 256, 0, stream>>>(slotA, slotB, wp1, b1, rb, stats, 1, 0);        // rb = x0 W0 + x1 W1
    spmm_wave<<<SG, 256, 0, stream>>>(rowptr, edges, slotB, slotA, 2.f, -1.f, slotA);  // x2 = 2Lx1 - x0
    spmm_wave<<<SG, 256, 0, stream>>>(rowptr, edges, slotA, slotB, 2.f, -1.f, slotB);  // x3 = 2Lx2 - x1
    gemm1_mfma<<<g1, 256, 0, stream>>>(slotA, slotB, wp1 + 16384, b1, rb, stats, 0, 1);// rb += x2 W2 + x3 W3

    finalize_k<<<1, 128, 0, stream>>>(stats, bn_gamma, bn_beta, ss);

    // ---- Chain 2 (Clenshaw, all SpMM on F=256) ----
    gemmC_mfma<<<g1, 256, 0, stream>>>(rb, wp2 + 3 * 8192, nullu, ss, slotA);          // P3 = y^ W3
    spmm_wave<<<SG, 256, 0, stream>>>(rowptr, edges, slotA, nullu, 2.f, 0.f, slotB);   // S  = 2L P3
    gemmC_mfma<<<g1, 256, 0, stream>>>(rb, wp2 + 2 * 8192, slotB, ss, slotC);          // P2 = y^ W2 + S
    spmm_wave<<<SG, 256, 0, stream>>>(rowptr, edges, slotC, slotA, 2.f, -1.f, slotA);  // U  = 2L P2 - P3
    gemmC_mfma<<<g1, 256, 0, stream>>>(rb, wp2 + 1 * 8192, slotA, ss, slotB);          // P1 = y^ W1 + U
    spmm_wave<<<SG, 256, 0, stream>>>(rowptr, edges, slotB, slotC, 1.f, -1.f, slotC);  // Tb = L P1 - P2
    gemm2_final<<<g2, 256, 0, stream>>>(rb, wp2, slotC, b2, x, ss, out);               // out = relu(y^ W0 + Tb + b2 + x)
}